// Round 4
// baseline (358.747 us; speedup 1.0000x reference)
//
#include <hip/hip_runtime.h>

constexpr int NZ   = 300, NX = 500, NPAD = 40;
constexpr int NZP  = NZ + NPAD;           // 340
constexpr int NXP  = NX + 2 * NPAD;       // 580 (divisible by 4)
constexpr int Bdim = 2, Cdim = 8;
constexpr int HW   = NZP * NXP;           // 197200
constexpr long S   = (long)Bdim * Cdim * HW; // 3155200
constexpr int NG   = NXP / 4;             // 145 column groups per row
constexpr int GTOT = Bdim * Cdim * NZP * NG; // 788800 threads (4 px each)
constexpr int BLK  = 320;                 // 5 waves; GTOT/BLK = 2465 exact
constexpr int GRID = GTOT / BLK;          // 2465
constexpr float DT = 1e-3f;
constexpr float A2 = (float)((1.0 / 24.0) / 10.0);   // a/DX
constexpr float B2 = (float)((9.0 / 8.0) / 10.0);    // b/DX
constexpr float COEF = 0.43173470493638357f;         // -ln(1e-5)*3*4000/(2*(DX*NPAD)^2)

__device__ __forceinline__ float dax_of(int j) {
    float ax = 1.0f;
    if (j < NPAD)            { int r = NPAD - 1 - j;    ax = COEF * (float)(r * r); }
    else if (j >= NX + NPAD) { int r = j - (NX + NPAD); ax = COEF * (float)(r * r); }
    return 1.0f - DT * ax;
}
__device__ __forceinline__ float daz_of(int i) {
    float az = 1.0f;
    if (i >= NZ) { int r = i - NZ; az = COEF * (float)(r * r); }
    return 1.0f - DT * az;
}

__device__ __forceinline__ float4 ld4(const float* p) { return *(const float4*)p; }
__device__ __forceinline__ float4 ld4c(const float* p, bool c) {
    float4 z = make_float4(0.f, 0.f, 0.f, 0.f);
    return c ? *(const float4*)p : z;
}
__device__ __forceinline__ float comp(const float4& v, int k) {
    switch (k) { case 0: return v.x; case 1: return v.y; case 2: return v.z; default: return v.w; }
}
__device__ __forceinline__ void setc(float4& v, int k, float s) {
    switch (k) { case 0: v.x = s; break; case 1: v.y = s; break; case 2: v.z = s; break; default: v.w = s; }
}
__device__ __forceinline__ void win12(float* w, float4 l, float4 m, float4 r) {
    w[0]=l.x; w[1]=l.y; w[2]=l.z; w[3]=l.w;
    w[4]=m.x; w[5]=m.y; w[6]=m.z; w[7]=m.w;
    w[8]=r.x; w[9]=r.y; w[10]=r.z; w[11]=r.w;
}

// ---------------- Kernel 1: velocity update (PML split), 4 px/thread ----------------
__global__ __launch_bounds__(BLK) void k_vel(
    const float* __restrict__ txx, const float* __restrict__ tzz, const float* __restrict__ txz,
    const float* __restrict__ vx_x, const float* __restrict__ vx_z,
    const float* __restrict__ vz_x, const float* __restrict__ vz_z,
    const float* __restrict__ rho,
    const float* __restrict__ fs, const int* __restrict__ zs, const int* __restrict__ xs,
    float* __restrict__ out)
{
    int g  = blockIdx.x * BLK + threadIdx.x;
    int jg = g % NG;
    int t  = g / NG;
    int i  = t % NZP;
    int bc = t / NZP;
    int cc = bc % Cdim;
    int b  = bc / Cdim;
    int jb = jg * 4;
    int p  = bc * HW + i * NXP + jb;      // [B*C,H,W] offset, 16B-aligned
    int mp = b  * HW + i * NXP + jb;      // [B,1,H,W] offset

    bool cl  = jg > 0,  cr  = jg < NG - 1;
    bool rm2 = i >= 2,  rm1 = i >= 1, rp1 = i + 1 < NZP, rp2 = i + 2 < NZP;

    // x-windows (row i)
    float4 txxl = ld4c(txx + p - 4, cl), txxm = ld4(txx + p), txxr = ld4c(txx + p + 4, cr);
    float4 txzl = ld4c(txz + p - 4, cl), txzm = ld4(txz + p), txzr = ld4c(txz + p + 4, cr);
    // z-rows (cols jb..jb+3)
    float4 txz_m2 = ld4c(txz + p - 2 * NXP, rm2);
    float4 txz_m1 = ld4c(txz + p - NXP,     rm1);
    float4 txz_p1 = ld4c(txz + p + NXP,     rp1);
    float4 tzz_m1 = ld4c(tzz + p - NXP,     rm1);
    float4 tzz_0  = ld4 (tzz + p);
    float4 tzz_p1 = ld4c(tzz + p + NXP,     rp1);
    float4 tzz_p2 = ld4c(tzz + p + 2 * NXP, rp2);

    // point-source injection into tzz (before z-derivative)
    int sz = zs[cc], sx = xs[cc] + NPAD;
    if (jg == (sx >> 2)) {
        float f = fs[b];
        int sk = sx & 3;
        float4 inj = make_float4(sk == 0 ? f : 0.f, sk == 1 ? f : 0.f,
                                 sk == 2 ? f : 0.f, sk == 3 ? f : 0.f);
        if (i - 1 == sz) { tzz_m1.x += inj.x; tzz_m1.y += inj.y; tzz_m1.z += inj.z; tzz_m1.w += inj.w; }
        if (i     == sz) { tzz_0.x  += inj.x; tzz_0.y  += inj.y; tzz_0.z  += inj.z; tzz_0.w  += inj.w; }
        if (i + 1 == sz) { tzz_p1.x += inj.x; tzz_p1.y += inj.y; tzz_p1.z += inj.z; tzz_p1.w += inj.w; }
        if (i + 2 == sz) { tzz_p2.x += inj.x; tzz_p2.y += inj.y; tzz_p2.z += inj.z; tzz_p2.w += inj.w; }
    }

    float wtxx[12], wtxz[12];
    win12(wtxx, txxl, txxm, txxr);
    win12(wtxz, txzl, txzm, txzr);

    float4 rh  = ld4(rho + mp);
    float4 vxx = ld4(vx_x + p), vxz = ld4(vx_z + p);
    float4 vzx = ld4(vz_x + p), vzz = ld4(vz_z + p);

    float daz = daz_of(i);
    float4 o_vx, o_vz, o_vxx, o_vxz, o_vzx, o_vzz;
    #pragma unroll
    for (int k = 0; k < 4; k++) {
        float dax  = dax_of(jb + k);
        float rinv = 1.0f / comp(rh, k);
        // KX on txx:  A2*(f[j-1]-f[j+2]) + B2*(f[j+1]-f[j])
        float vtxx  = A2 * (wtxx[3 + k] - wtxx[6 + k]) + B2 * (wtxx[5 + k] - wtxx[4 + k]);
        // KXU on txz: A2*(f[j-2]-f[j+1]) + B2*(f[j]-f[j-1])
        float vtxzx = A2 * (wtxz[2 + k] - wtxz[5 + k]) + B2 * (wtxz[4 + k] - wtxz[3 + k]);
        // KZU on txz: A2*(f[i-2]-f[i+1]) + B2*(f[i]-f[i-1])
        float vtxzz = A2 * (comp(txz_m2, k) - comp(txz_p1, k)) + B2 * (comp(txzm, k) - comp(txz_m1, k));
        // KZ on tzz:  A2*(f[i-1]-f[i+2]) + B2*(f[i+1]-f[i])
        float vtzzz = A2 * (comp(tzz_m1, k) - comp(tzz_p2, k)) + B2 * (comp(tzz_p1, k) - comp(tzz_0, k));

        float nvx_x = dax * comp(vxx, k) + DT * (vtxx  * rinv);
        float nvx_z = daz * comp(vxz, k) + DT * (vtxzz * rinv);
        float nvz_x = dax * comp(vzx, k) + DT * (vtxzx * rinv);
        float nvz_z = daz * comp(vzz, k) + DT * (vtzzz * rinv);

        setc(o_vx,  k, nvx_x + nvx_z);
        setc(o_vz,  k, nvz_x + nvz_z);
        setc(o_vxx, k, nvx_x);
        setc(o_vxz, k, nvx_z);
        setc(o_vzx, k, nvz_x);
        setc(o_vzz, k, nvz_z);
    }
    *(float4*)(out + 0 * S + p) = o_vx;
    *(float4*)(out + 1 * S + p) = o_vz;
    *(float4*)(out + 5 * S + p) = o_vxx;
    *(float4*)(out + 6 * S + p) = o_vxz;
    *(float4*)(out + 7 * S + p) = o_vzx;
    *(float4*)(out + 8 * S + p) = o_vzz;
}

// ---------------- Kernel 2: stress update (PML split), 4 px/thread ----------------
__global__ __launch_bounds__(BLK) void k_stress(
    const float* __restrict__ txx_x, const float* __restrict__ txx_z,
    const float* __restrict__ tzz_x, const float* __restrict__ tzz_z,
    const float* __restrict__ txz_x, const float* __restrict__ txz_z,
    const float* __restrict__ vp, const float* __restrict__ vs, const float* __restrict__ rho,
    float* __restrict__ out)
{
    int g  = blockIdx.x * BLK + threadIdx.x;
    int jg = g % NG;
    int t  = g / NG;
    int i  = t % NZP;
    int bc = t / NZP;
    int b  = bc / Cdim;
    int jb = jg * 4;
    int p  = bc * HW + i * NXP + jb;
    int mp = b  * HW + i * NXP + jb;

    bool cl  = jg > 0,  cr  = jg < NG - 1;
    bool rm2 = i >= 2,  rm1 = i >= 1, rp1 = i + 1 < NZP, rp2 = i + 2 < NZP;

    const float* VX = out + 0 * S;
    const float* VZ = out + 1 * S;

    float4 vxl = ld4c(VX + p - 4, cl), vxm = ld4(VX + p), vxr = ld4c(VX + p + 4, cr);
    float4 vzl = ld4c(VZ + p - 4, cl), vzm = ld4(VZ + p), vzr = ld4c(VZ + p + 4, cr);
    float4 vx_m1 = ld4c(VX + p - NXP,     rm1);
    float4 vx_p1 = ld4c(VX + p + NXP,     rp1);
    float4 vx_p2 = ld4c(VX + p + 2 * NXP, rp2);
    float4 vz_m2 = ld4c(VZ + p - 2 * NXP, rm2);
    float4 vz_m1 = ld4c(VZ + p - NXP,     rm1);
    float4 vz_p1 = ld4c(VZ + p + NXP,     rp1);

    float wvx[12], wvz[12];
    win12(wvx, vxl, vxm, vxr);
    win12(wvz, vzl, vzm, vzr);

    float4 vp4 = ld4(vp + mp), vs4 = ld4(vs + mp), rh4 = ld4(rho + mp);
    float4 sxx_x = ld4(txx_x + p), sxx_z = ld4(txx_z + p);
    float4 szz_x = ld4(tzz_x + p), szz_z = ld4(tzz_z + p);
    float4 sxz_x = ld4(txz_x + p), sxz_z = ld4(txz_z + p);

    float daz = daz_of(i);
    float4 o_txx, o_tzz, o_txz, o_txxx, o_txxz, o_tzzx, o_tzzz, o_txzx, o_txzz;
    #pragma unroll
    for (int k = 0; k < 4; k++) {
        float dax = dax_of(jb + k);
        // KXU on vx: A2*(f[j-2]-f[j+1]) + B2*(f[j]-f[j-1])
        float vvxx = A2 * (wvx[2 + k] - wvx[5 + k]) + B2 * (wvx[4 + k] - wvx[3 + k]);
        // KZ on vx:  A2*(f[i-1]-f[i+2]) + B2*(f[i+1]-f[i])
        float vvxz = A2 * (comp(vx_m1, k) - comp(vx_p2, k)) + B2 * (comp(vx_p1, k) - comp(vxm, k));
        // KX on vz:  A2*(f[j-1]-f[j+2]) + B2*(f[j+1]-f[j])
        float vvzx = A2 * (wvz[3 + k] - wvz[6 + k]) + B2 * (wvz[5 + k] - wvz[4 + k]);
        // KZU on vz: A2*(f[i-2]-f[i+1]) + B2*(f[i]-f[i-1])
        float vvzz = A2 * (comp(vz_m2, k) - comp(vz_p1, k)) + B2 * (comp(vzm, k) - comp(vz_m1, k));

        float vpv = comp(vp4, k), vsv = comp(vs4, k), rh = comp(rh4, k);
        float lam2mu = vpv * vpv * rh;
        float mu     = vsv * vsv * rh;
        float lam    = lam2mu - 2.0f * mu;

        float ntxx_x = dax * comp(sxx_x, k) + DT * lam2mu * vvxx;
        float ntxx_z = daz * comp(sxx_z, k) + DT * lam    * vvzz;
        float ntzz_x = dax * comp(szz_x, k) + DT * lam    * vvxx;
        float ntzz_z = daz * comp(szz_z, k) + DT * lam2mu * vvzz;
        float ntxz_x = dax * comp(sxz_x, k) + DT * mu     * vvzx;
        float ntxz_z = daz * comp(sxz_z, k) + DT * mu     * vvxz;

        setc(o_txx,  k, ntxx_x + ntxx_z);
        setc(o_tzz,  k, ntzz_x + ntzz_z);
        setc(o_txz,  k, ntxz_x + ntxz_z);
        setc(o_txxx, k, ntxx_x);
        setc(o_txxz, k, ntxx_z);
        setc(o_tzzx, k, ntzz_x);
        setc(o_tzzz, k, ntzz_z);
        setc(o_txzx, k, ntxz_x);
        setc(o_txzz, k, ntxz_z);
    }
    *(float4*)(out +  2 * S + p) = o_txx;
    *(float4*)(out +  3 * S + p) = o_tzz;
    *(float4*)(out +  4 * S + p) = o_txz;
    *(float4*)(out +  9 * S + p) = o_txxx;
    *(float4*)(out + 10 * S + p) = o_txxz;
    *(float4*)(out + 11 * S + p) = o_tzzx;
    *(float4*)(out + 12 * S + p) = o_tzzz;
    *(float4*)(out + 13 * S + p) = o_txzx;
    *(float4*)(out + 14 * S + p) = o_txzz;
}

extern "C" void kernel_launch(void* const* d_in, const int* in_sizes, int n_in,
                              void* d_out, int out_size, void* d_ws, size_t ws_size,
                              hipStream_t stream) {
    const float* txx   = (const float*)d_in[0];
    const float* tzz   = (const float*)d_in[1];
    const float* txz   = (const float*)d_in[2];
    const float* vx_x  = (const float*)d_in[3];
    const float* vx_z  = (const float*)d_in[4];
    const float* vz_x  = (const float*)d_in[5];
    const float* vz_z  = (const float*)d_in[6];
    const float* txx_x = (const float*)d_in[7];
    const float* txx_z = (const float*)d_in[8];
    const float* tzz_x = (const float*)d_in[9];
    const float* tzz_z = (const float*)d_in[10];
    const float* txz_x = (const float*)d_in[11];
    const float* txz_z = (const float*)d_in[12];
    const float* vp    = (const float*)d_in[13];
    const float* vs    = (const float*)d_in[14];
    const float* rho   = (const float*)d_in[15];
    const float* fs    = (const float*)d_in[16];
    const int*   zs    = (const int*)d_in[17];
    const int*   xs    = (const int*)d_in[18];
    float* out = (float*)d_out;

    k_vel<<<GRID, BLK, 0, stream>>>(txx, tzz, txz, vx_x, vx_z, vz_x, vz_z,
                                    rho, fs, zs, xs, out);
    k_stress<<<GRID, BLK, 0, stream>>>(txx_x, txx_z, tzz_x, tzz_z, txz_x, txz_z,
                                       vp, vs, rho, out);
}